// Round 1
// baseline (73.740 us; speedup 1.0000x reference)
//
#include <hip/hip_runtime.h>
#include <math.h>

#define BB 512
#define CC 256
typedef unsigned long long u64;

__device__ inline float wave_sum(float v) {
    #pragma unroll
    for (int off = 32; off > 0; off >>= 1) v += __shfl_down(v, off, 64);
    return v;
}
__device__ inline float wave_max(float v) {
    #pragma unroll
    for (int off = 32; off > 0; off >>= 1) v = fmaxf(v, __shfl_down(v, off, 64));
    return v;
}

// block-wide sum for 256 threads (4 waves). red must hold >=4 floats.
__device__ inline float block_sum_256(float v, float* red, int tid) {
    int wave = tid >> 6, lane = tid & 63;
    float w = wave_sum(v);
    __syncthreads();               // protect red from previous use
    if (lane == 0) red[wave] = w;
    __syncthreads();
    return red[0] + red[1] + red[2] + red[3];
}
__device__ inline float block_max_256(float v, float* red, int tid) {
    int wave = tid >> 6, lane = tid & 63;
    float w = wave_max(v);
    __syncthreads();
    if (lane == 0) red[wave] = w;
    __syncthreads();
    return fmaxf(fmaxf(red[0], red[1]), fmaxf(red[2], red[3]));
}

// ---------------- Kernel 1: pack concepts to bitsets + masked BCE partials ----
__global__ __launch_bounds__(256) void pack_bce_kernel(
        const int* __restrict__ mc, const float* __restrict__ cl,
        u64* __restrict__ bits, float* __restrict__ bce_out, float* __restrict__ msk_out) {
    int i = blockIdx.x, tid = threadIdx.x;
    int c = mc[i * CC + tid];
    u64 ballot = __ballot(c == 1);
    int wave = tid >> 6, lane = tid & 63;
    if (lane == 0) bits[i * 4 + wave] = ballot;

    float x = cl[i * CC + tid];
    float mask = (c != -1) ? 1.0f : 0.0f;
    float t = (c == 1) ? 1.0f : 0.0f;
    // bce = max(x,0) - x*t + log1p(exp(-|x|))
    float bce = (fmaxf(x, 0.0f) - x * t + log1pf(__expf(-fabsf(x)))) * mask;

    __shared__ float red[4];
    float sb = block_sum_256(bce, red, tid);
    float sm = block_sum_256(mask, red, tid);
    if (tid == 0) { bce_out[i] = sb; msk_out[i] = sm; }
}

// ---------------- Kernel 2: one block per row i ------------------------------
// Computes: a_j = 5 * jaccard(i,j); row softmax stats over a; then for each of
// the 3 logit matrices X the row cross term  Sx/Z - Mx - log Zx.
__global__ __launch_bounds__(256) void row_kernel(
        const float* __restrict__ lpi, const float* __restrict__ lpt,
        const float* __restrict__ cis, const u64* __restrict__ bits,
        float* __restrict__ ent_o, float* __restrict__ ci_o,
        float* __restrict__ ct_o, float* __restrict__ cc_o) {
    int i = blockIdx.x, tid = threadIdx.x;
    __shared__ float a[BB];
    __shared__ float red[4];

    u64 m0 = bits[i * 4 + 0], m1 = bits[i * 4 + 1];
    u64 m2 = bits[i * 4 + 2], m3 = bits[i * 4 + 3];

    #pragma unroll
    for (int jj = 0; jj < 2; ++jj) {
        int j = tid + jj * 256;
        const u64* bj = bits + j * 4;
        u64 b0 = bj[0], b1 = bj[1], b2 = bj[2], b3 = bj[3];
        int inter = __popcll(m0 & b0) + __popcll(m1 & b1) + __popcll(m2 & b2) + __popcll(m3 & b3);
        int uni   = __popcll(m0 | b0) + __popcll(m1 | b1) + __popcll(m2 | b2) + __popcll(m3 | b3);
        float s = (uni > 0) ? ((float)inter / (float)uni) : 0.0f;
        a[j] = s * 5.0f;   // sim / TEMPERATURE
    }
    __syncthreads();

    float a0 = a[tid], a1 = a[tid + 256];
    float M  = block_max_256(fmaxf(a0, a1), red, tid);
    float e0 = __expf(a0 - M), e1 = __expf(a1 - M);
    float Z  = block_sum_256(e0 + e1, red, tid);
    float SA = block_sum_256(e0 * a0 + e1 * a1, red, tid);
    float invZ = 1.0f / Z;
    if (tid == 0) ent_o[i] = SA * invZ - M - logf(Z);   // sum t*log t

    const float* rows[3] = { lpi + (size_t)i * BB, lpt + (size_t)i * BB, cis + (size_t)i * BB };
    float* outs[3] = { ci_o, ct_o, cc_o };
    #pragma unroll
    for (int k = 0; k < 3; ++k) {
        const float* xr = rows[k];
        float x0 = xr[tid], x1 = xr[tid + 256];
        float MX = block_max_256(fmaxf(x0, x1), red, tid);
        float ZX = block_sum_256(__expf(x0 - MX) + __expf(x1 - MX), red, tid);
        float SX = block_sum_256(e0 * x0 + e1 * x1, red, tid);
        if (tid == 0) outs[k][i] = SX * invZ - MX - logf(ZX);  // sum t*log_softmax(x)
    }
}

// ---------------- Kernel 3: final reduction + combine ------------------------
__global__ __launch_bounds__(512) void finalize_kernel(
        const float* __restrict__ ent, const float* __restrict__ ci,
        const float* __restrict__ ct, const float* __restrict__ cc,
        const float* __restrict__ bce, const float* __restrict__ msk,
        float* __restrict__ out) {
    int tid = threadIdx.x;
    int wave = tid >> 6, lane = tid & 63;
    __shared__ float red[8][6];
    float v[6] = { ent[tid], ci[tid], ct[tid], cc[tid], bce[tid], msk[tid] };
    #pragma unroll
    for (int k = 0; k < 6; ++k) {
        float w = wave_sum(v[k]);
        if (lane == 0) red[wave][k] = w;
    }
    __syncthreads();
    if (tid == 0) {
        float s[6];
        #pragma unroll
        for (int k = 0; k < 6; ++k) {
            float acc = 0.0f;
            #pragma unroll
            for (int w = 0; w < 8; ++w) acc += red[w][k];
            s[k] = acc;
        }
        float ENT = s[0], CI = s[1], CT = s[2], CCs = s[3], BCE = s[4], MS = s[5];
        float kl_i = (ENT - CI) / (float)BB;
        float kl_t = (ENT - CT) / (float)BB;
        float kl_c = (ENT - CCs) / (float)BB;
        float concept = BCE / (MS + 1e-8f);
        out[0] = 0.5f * (kl_i + kl_t) + 0.2f * concept + 0.2f * kl_c;
    }
}

extern "C" void kernel_launch(void* const* d_in, const int* in_sizes, int n_in,
                              void* d_out, int out_size, void* d_ws, size_t ws_size,
                              hipStream_t stream) {
    const float* lpi = (const float*)d_in[0];   // logits_per_image [512,512]
    const float* lpt = (const float*)d_in[1];   // logits_per_text  [512,512]
    const float* cl  = (const float*)d_in[2];   // concepts_logits  [512,256]
    const float* cis = (const float*)d_in[3];   // concepts_image_similarity [512,512]
    const int*   mc  = (const int*)d_in[4];     // medical_concepts [512,256]

    char* ws = (char*)d_ws;
    u64*   bits = (u64*)ws;                        // 512*4*8  = 16384 B
    float* ent  = (float*)(ws + 16384);            // 512*4    =  2048 B
    float* ci   = ent + BB;
    float* ct   = ci + BB;
    float* cc   = ct + BB;
    float* bce  = cc + BB;
    float* msk  = bce + BB;                        // total ~28 KB

    float* out = (float*)d_out;

    pack_bce_kernel<<<BB, CC, 0, stream>>>(mc, cl, bits, bce, msk);
    row_kernel<<<BB, 256, 0, stream>>>(lpi, lpt, cis, bits, ent, ci, ct, cc);
    finalize_kernel<<<1, BB, 0, stream>>>(ent, ci, ct, cc, bce, msk, out);
}